// Round 4
// baseline (508.855 us; speedup 1.0000x reference)
//
#include <hip/hip_runtime.h>

#define BLOCK  256
#define UNROLL 4
#define CHUNK4 (BLOCK * UNROLL)   // float4 elements per block = 1024

// Mahalanobis AR(1) loss:
//   quad[b] = sum d_i^2 + 2*coef*sum d_i*d_{i+1},  d = (y_true-y_pred)*mask(t<n[b])
//   out = mean_b quad[b]/n[b]
// D = 64 floats = 16 float4/row; lane handles col4 = tid&15.
//
// R4: compiler sank register prefetches 3 rounds running (VGPR=40/44 proves
// it). global_load_lds stages to LDS instead — nothing to sink, 8x16B async
// per thread guaranteed in flight (32 KB/block), drained once at the barrier.
__global__ __launch_bounds__(BLOCK) void mahal_main(
    const float4* __restrict__ yt4,
    const float4* __restrict__ yp4,
    const float*  __restrict__ param,
    const int*    __restrict__ n,
    float* __restrict__ partial,
    int total_vec4)
{
    __shared__ float4 sA[CHUNK4];
    __shared__ float4 sB[CHUNK4];

    float t = param[0];
    float p = 2.0f / (1.0f + __expf(-t)) - 1.0f;
    float coef2 = -2.0f * p / (1.0f + p * p);   // 2*coef

    const int tid  = threadIdx.x;
    const int wave = tid >> 6;
    const int lane = tid & 63;
    const int gbase = blockIdx.x * CHUNK4;

    const int col4 = tid & 15;      // CHUNK4 multiple of 16 => same for all j
    const int e0   = col4 << 2;
    const bool not_last = (col4 != 15);
    float acc = 0.0f;

    if (gbase + CHUNK4 <= total_vec4) {
        // ---- async stage: 8 x 16B per thread, all in flight before barrier ----
        int vv[UNROLL];
        #pragma unroll
        for (int j = 0; j < UNROLL; ++j) {
            int k = j * BLOCK + wave * 64;          // wave-uniform LDS offset
            __builtin_amdgcn_global_load_lds(
                (const __attribute__((address_space(1))) void*)(yt4 + gbase + k + lane),
                (__attribute__((address_space(3))) void*)(&sA[k]), 16, 0, 0);
            __builtin_amdgcn_global_load_lds(
                (const __attribute__((address_space(1))) void*)(yp4 + gbase + k + lane),
                (__attribute__((address_space(3))) void*)(&sB[k]), 16, 0, 0);
        }
        #pragma unroll
        for (int j = 0; j < UNROLL; ++j)
            vv[j] = n[(gbase + j * BLOCK + tid) >> 4];   // 16 lanes share a dword

        __syncthreads();   // drains vmcnt (staging) before LDS reads

        #pragma unroll
        for (int j = 0; j < UNROLL; ++j) {
            int k = j * BLOCK + tid;
            float4 a = sA[k];      // ds_read_b128, 2-way bank alias (free)
            float4 b = sB[k];
            int v = vv[j];
            float d0 = (e0 + 0 < v) ? (a.x - b.x) : 0.0f;
            float d1 = (e0 + 1 < v) ? (a.y - b.y) : 0.0f;
            float d2 = (e0 + 2 < v) ? (a.z - b.z) : 0.0f;
            float d3 = (e0 + 3 < v) ? (a.w - b.w) : 0.0f;
            float nb = __shfl_down(d0, 1, 64);          // pair (e0+3, e0+4)
            float sumsq = d0 * d0 + d1 * d1 + d2 * d2 + d3 * d3;
            float cross = d0 * d1 + d1 * d2 + d2 * d3;
            if (not_last) cross += d3 * nb;
            float q  = fmaf(coef2, cross, sumsq);
            float rv = __builtin_amdgcn_rcpf((float)(v > 0 ? v : 1));
            acc = fmaf(q, rv, acc);
        }
    } else {
        // tail block (block-uniform branch): plain guarded loads, no LDS
        #pragma unroll
        for (int j = 0; j < UNROLL; ++j) {
            int g = gbase + j * BLOCK + tid;
            int v = 0;
            float4 a = make_float4(0.f, 0.f, 0.f, 0.f);
            float4 b = a;
            if (g < total_vec4) { a = yt4[g]; b = yp4[g]; v = n[g >> 4]; }
            float d0 = (e0 + 0 < v) ? (a.x - b.x) : 0.0f;
            float d1 = (e0 + 1 < v) ? (a.y - b.y) : 0.0f;
            float d2 = (e0 + 2 < v) ? (a.z - b.z) : 0.0f;
            float d3 = (e0 + 3 < v) ? (a.w - b.w) : 0.0f;
            float nb = __shfl_down(d0, 1, 64);
            float sumsq = d0 * d0 + d1 * d1 + d2 * d2 + d3 * d3;
            float cross = d0 * d1 + d1 * d2 + d2 * d3;
            if (not_last) cross += d3 * nb;
            float q  = fmaf(coef2, cross, sumsq);
            float rv = __builtin_amdgcn_rcpf((float)(v > 0 ? v : 1));
            acc = fmaf(q, rv, acc);
        }
    }

    // wave reduction (64 lanes)
    #pragma unroll
    for (int off = 32; off >= 1; off >>= 1)
        acc += __shfl_down(acc, off, 64);

    __shared__ float smem[BLOCK / 64];
    if (lane == 0) smem[wave] = acc;
    __syncthreads();
    if (tid == 0) {
        float s = 0.0f;
        #pragma unroll
        for (int i = 0; i < BLOCK / 64; ++i) s += smem[i];
        partial[blockIdx.x] = s;
    }
}

// Single-block reduction of per-block partials; writes the final mean.
__global__ __launch_bounds__(256) void mahal_finish(
    const float* __restrict__ partial,
    float* __restrict__ out,
    int nblocks, float invB)
{
    float acc = 0.0f;
    if ((nblocks & 3) == 0) {
        const float4* p4 = (const float4*)partial;
        int n4 = nblocks >> 2;
        for (int i = threadIdx.x; i < n4; i += 256) {
            float4 v = p4[i];
            acc += v.x + v.y + v.z + v.w;
        }
    } else {
        for (int i = threadIdx.x; i < nblocks; i += 256)
            acc += partial[i];
    }
    #pragma unroll
    for (int off = 32; off >= 1; off >>= 1)
        acc += __shfl_down(acc, off, 64);
    __shared__ float smem[4];
    int lane = threadIdx.x & 63;
    int wid  = threadIdx.x >> 6;
    if (lane == 0) smem[wid] = acc;
    __syncthreads();
    if (threadIdx.x == 0)
        out[0] = (smem[0] + smem[1] + smem[2] + smem[3]) * invB;
}

extern "C" void kernel_launch(void* const* d_in, const int* in_sizes, int n_in,
                              void* d_out, int out_size, void* d_ws, size_t ws_size,
                              hipStream_t stream) {
    const float* y_true = (const float*)d_in[0];
    const float* y_pred = (const float*)d_in[1];
    const float* param  = (const float*)d_in[2];
    const int*   n      = (const int*)d_in[3];
    float* out = (float*)d_out;

    int total = in_sizes[0];        // B*D
    int B     = in_sizes[3];        // rows
    int total_vec4 = total / 4;
    float invB = 1.0f / (float)B;

    int blocks = (total_vec4 + CHUNK4 - 1) / CHUNK4;   // 16384 at B=1M, D=64
    float* partial = (float*)d_ws;                     // blocks*4 bytes

    mahal_main<<<blocks, BLOCK, 0, stream>>>((const float4*)y_true,
                                             (const float4*)y_pred,
                                             param, n, partial, total_vec4);
    mahal_finish<<<1, 256, 0, stream>>>(partial, out, blocks, invB);
}